// Round 8
// baseline (256.848 us; speedup 1.0000x reference)
//
#include <hip/hip_runtime.h>
#include <stdint.h>
#include <stddef.h>

typedef unsigned short u16;
typedef __bf16 bf16x8 __attribute__((ext_vector_type(8)));
typedef float f32x4 __attribute__((ext_vector_type(4)));
typedef float f32x16 __attribute__((ext_vector_type(16)));
typedef u16 u16x8 __attribute__((ext_vector_type(8)));
typedef unsigned uint32x2 __attribute__((ext_vector_type(2)));

#define SEQ    1024
#define DEMB   1024
#define MROWS  4096
#define NHEAD  16
#define HD     64
#define QSCALE 0.125f
#define LN_EPS 1e-5f

// round-to-nearest-even fp32 -> bf16 (raw bits)
static __device__ __forceinline__ u16 f2bf(float f) {
  union { float f; unsigned u; } c; c.f = f;
  unsigned r = c.u + 0x7FFFu + ((c.u >> 16) & 1u);
  return (u16)(r >> 16);
}
static __device__ __forceinline__ float bf2f(unsigned h) {
  union { unsigned u; float f; } c; c.u = h << 16; return c.f;
}
// pack two fp32 -> one u32 of 2 bf16 (compiler fuses to v_cvt_pk_bf16_f32)
static __device__ __forceinline__ unsigned pack2bf(float a, float b) {
  union { __bf16 h; u16 u; } x, y; x.h = (__bf16)a; y.h = (__bf16)b;
  return (unsigned)x.u | ((unsigned)y.u << 16);
}

// async global->LDS, 16B per lane; LDS dest = wave-uniform base + lane*16
static __device__ __forceinline__ void gload16(const void* g, void* l) {
  __builtin_amdgcn_global_load_lds((const __attribute__((address_space(1))) void*)g,
                                   (__attribute__((address_space(3))) void*)l, 16, 0, 0);
}

// ---------------- fp32 -> bf16 convert: x (4M) + Wq/Wk/Wv/Wo (4M) -----------
__global__ void cvt_kernel(const float* __restrict__ x,
                           const float* __restrict__ wq, const float* __restrict__ wk,
                           const float* __restrict__ wv, const float* __restrict__ wo,
                           u16* __restrict__ xb, u16* __restrict__ wb) {
  size_t e = ((size_t)blockIdx.x * blockDim.x + threadIdx.x) * 8;
  const float* src; u16* dst; size_t off;
  if (e < (size_t)MROWS * DEMB) { src = x; dst = xb; off = e; }
  else {
    size_t we = e - (size_t)MROWS * DEMB;
    int plane = (int)(we >> 20);
    src = (plane == 0) ? wq : (plane == 1) ? wk : (plane == 2) ? wv : wo;
    dst = wb + ((size_t)plane << 20);
    off = we & ((1u << 20) - 1);
  }
  float4 a = *(const float4*)(src + off);
  float4 b = *(const float4*)(src + off + 4);
  u16 o[8] = { f2bf(a.x), f2bf(a.y), f2bf(a.z), f2bf(a.w),
               f2bf(b.x), f2bf(b.y), f2bf(b.z), f2bf(b.w) };
  uint4 pk;
  pk.x = (unsigned)o[0] | ((unsigned)o[1] << 16);
  pk.y = (unsigned)o[2] | ((unsigned)o[3] << 16);
  pk.z = (unsigned)o[4] | ((unsigned)o[5] << 16);
  pk.w = (unsigned)o[6] | ((unsigned)o[7] << 16);
  *(uint4*)(dst + off) = pk;
}

// ---------------- bf16 GEMM  C[m,n] = sum_k A[m,k] * W[n,k]  (bf16 out) -----
__global__ __launch_bounds__(256)
void gemm_bt(const u16* __restrict__ A, const u16* __restrict__ B0,
             const u16* __restrict__ B1, const u16* __restrict__ B2,
             u16* __restrict__ C, int M, int N, int K) {
  __shared__ u16 lA[128 * 32];
  __shared__ u16 lB[128 * 32];
  const u16* Bp = (blockIdx.z == 0) ? B0 : (blockIdx.z == 1) ? B1 : B2;
  u16* Cp = C + (size_t)blockIdx.z * ((size_t)M * N);
  const int tid = threadIdx.x;
  const int w = tid >> 6, l = tid & 63;
  const int lr = l & 15, lg = l >> 4;
  const int m0 = blockIdx.x * 128, n0 = blockIdx.y * 128;
  const int wm = (w & 1) * 64, wn = (w >> 1) * 64;
  f32x4 acc[4][4] = {};
  const int cid0 = w * 64 + l;
  const int cid1 = 256 + w * 64 + l;
  const int rowA0 = cid0 >> 2, kc0 = (cid0 & 3) * 8;
  const int rowA1 = cid1 >> 2, kc1 = (cid1 & 3) * 8;
  for (int kt = 0; kt < K; kt += 32) {
    __syncthreads();
    gload16(A  + (size_t)(m0 + rowA0) * K + kt + kc0, lA + (size_t)(w * 64) * 8);
    gload16(A  + (size_t)(m0 + rowA1) * K + kt + kc1, lA + (size_t)(256 + w * 64) * 8);
    gload16(Bp + (size_t)(n0 + rowA0) * K + kt + kc0, lB + (size_t)(w * 64) * 8);
    gload16(Bp + (size_t)(n0 + rowA1) * K + kt + kc1, lB + (size_t)(256 + w * 64) * 8);
    __syncthreads();
    bf16x8 af[4], bfg[4];
#pragma unroll
    for (int mb = 0; mb < 4; ++mb) {
      union { u16x8 u; bf16x8 v; } cv;
      cv.u = *(const u16x8*)(lA + (wm + mb * 16 + lr) * 32 + lg * 8);
      af[mb] = cv.v;
    }
#pragma unroll
    for (int nb = 0; nb < 4; ++nb) {
      union { u16x8 u; bf16x8 v; } cv;
      cv.u = *(const u16x8*)(lB + (wn + nb * 16 + lr) * 32 + lg * 8);
      bfg[nb] = cv.v;
    }
#pragma unroll
    for (int mb = 0; mb < 4; ++mb)
#pragma unroll
      for (int nb = 0; nb < 4; ++nb)
        acc[mb][nb] = __builtin_amdgcn_mfma_f32_16x16x32_bf16(af[mb], bfg[nb], acc[mb][nb], 0, 0, 0);
  }
#pragma unroll
  for (int mb = 0; mb < 4; ++mb)
#pragma unroll
    for (int nb = 0; nb < 4; ++nb)
#pragma unroll
      for (int r = 0; r < 4; ++r) {
        int row = m0 + wm + mb * 16 + lg * 4 + r;
        int col = n0 + wn + nb * 16 + lr;
        Cp[(size_t)row * N + col] = f2bf(acc[mb][nb][r]);
      }
}

// ---------------- block-wide (256t) sum + sumsq reduce ----------------------
static __device__ __forceinline__ void block_reduce2(float& s1, float& s2, float* red) {
#pragma unroll
  for (int o = 32; o > 0; o >>= 1) { s1 += __shfl_xor(s1, o); s2 += __shfl_xor(s2, o); }
  int w = threadIdx.x >> 6, l = threadIdx.x & 63;
  if (l == 0) { red[w * 2] = s1; red[w * 2 + 1] = s2; }
  __syncthreads();
  s1 = red[0] + red[2] + red[4] + red[6];
  s2 = red[1] + red[3] + red[5] + red[7];
}

// ---------------- LN over QKV proj rows -> bf16 head layout [B,H,S,64] ------
__global__ void ln_qkv_kernel(const u16* __restrict__ projb,
                              const float* __restrict__ bq, const float* __restrict__ bk,
                              const float* __restrict__ bv,
                              const float* __restrict__ qg, const float* __restrict__ qb,
                              const float* __restrict__ kg, const float* __restrict__ kb,
                              const float* __restrict__ vg, const float* __restrict__ vb,
                              u16* __restrict__ Qh, u16* __restrict__ Kh, u16* __restrict__ Vh) {
  __shared__ float red[8];
  const int row = blockIdx.x & (MROWS - 1);
  const int plane = blockIdx.x >> 12;
  const float* bias; const float* gam; const float* bet; u16* op; float scl;
  if (plane == 0)      { bias = bq; gam = qg; bet = qb; op = Qh; scl = QSCALE; }
  else if (plane == 1) { bias = bk; gam = kg; bet = kb; op = Kh; scl = 1.f; }
  else                 { bias = bv; gam = vg; bet = vb; op = Vh; scl = 1.f; }
  const u16* src = projb + ((size_t)plane * MROWS + row) * DEMB;
  const int t = threadIdx.x;
  uint2 pv = *(const uint2*)(src + t * 4);
  float4 v;
  v.x = bf2f(pv.x & 0xffffu); v.y = bf2f(pv.x >> 16);
  v.z = bf2f(pv.y & 0xffffu); v.w = bf2f(pv.y >> 16);
  float4 bz = *(const float4*)(bias + t * 4);
  v.x += bz.x; v.y += bz.y; v.z += bz.z; v.w += bz.w;
  float s1 = v.x + v.y + v.z + v.w;
  float s2 = v.x * v.x + v.y * v.y + v.z * v.z + v.w * v.w;
  block_reduce2(s1, s2, red);
  const float mean = s1 * (1.f / DEMB);
  const float var = s2 * (1.f / DEMB) - mean * mean;
  const float rstd = rsqrtf(var + LN_EPS);
  float4 gg = *(const float4*)(gam + t * 4);
  float4 bb = *(const float4*)(bet + t * 4);
  u16 o0 = f2bf(((v.x - mean) * rstd * gg.x + bb.x) * scl);
  u16 o1 = f2bf(((v.y - mean) * rstd * gg.y + bb.y) * scl);
  u16 o2 = f2bf(((v.z - mean) * rstd * gg.z + bb.z) * scl);
  u16 o3 = f2bf(((v.w - mean) * rstd * gg.w + bb.w) * scl);
  const int b = row >> 10, s = row & (SEQ - 1);
  const int h = t >> 4;
  u16* dst = op + ((size_t)(b * NHEAD + h) * SEQ + s) * HD + (t & 15) * 4;
  uint2 pk;
  pk.x = (unsigned)o0 | ((unsigned)o1 << 16);
  pk.y = (unsigned)o2 | ((unsigned)o3 << 16);
  *(uint2*)dst = pk;
}

// ---------------- V transpose: Vtmp[bh][s][d] -> VT[bh][d][s] ---------------
__global__ __launch_bounds__(256)
void vtr_kernel(const u16* __restrict__ Vtmp, u16* __restrict__ VT) {
  __shared__ u16 t[64][72];
  const int stile = blockIdx.x & 15, bh = blockIdx.x >> 4;
  const u16* src = Vtmp + ((size_t)bh * SEQ + stile * 64) * HD;
  const int tid = threadIdx.x;
  {
    const int c0 = tid * 2;
    const int r = c0 >> 3, c = c0 & 7;
    uint4 v0 = *(const uint4*)(src + (size_t)r * HD + c * 8);
    uint4 v1 = *(const uint4*)(src + (size_t)r * HD + (c + 1) * 8);
    *(uint4*)&t[r][c * 8] = v0;
    *(uint4*)&t[r][(c + 1) * 8] = v1;
  }
  __syncthreads();
  const int d = tid >> 2, sc = tid & 3;
  u16 buf[16];
#pragma unroll
  for (int j = 0; j < 16; ++j) buf[j] = t[sc * 16 + j][d];
  u16* dst = VT + ((size_t)bh * HD + d) * SEQ + stile * 64 + sc * 16;
  *(uint4*)(dst)     = *(uint4*)&buf[0];
  *(uint4*)(dst + 8) = *(uint4*)&buf[8];
}

// ---------------- attention: swapped QK^T, 32x32x16 MFMA, in-register -------
// 128t block = 2 waves k-split over same 32 q-rows (512 k each).
// S^T = mfma(K,Q): lane holds P[q=lane&31][32 k-vals] -> softmax lane-local;
// P->bf16 pack (cvt_pk) + permlane32_swap builds PV A-frags; no LDS in loop.
__global__ __launch_bounds__(128)
void attn_kernel(const u16* __restrict__ Qh, const u16* __restrict__ Kh,
                 const u16* __restrict__ VT, u16* __restrict__ AO) {
  __shared__ float oL[32][64];       // wave-1 partial O
  __shared__ float rsL[32];          // wave-1 partial row sums
  const int bid = blockIdx.x;
  const int wg = (bid & 7) * 256 + (bid >> 3);   // bijective: 2048 = 8*256
  const int qt = wg & 31, bh = wg >> 5;          // 8 heads per XCD chunk
  const int b = bh >> 4, h = bh & 15;
  const u16* Qp = Qh + (size_t)bh * SEQ * HD;
  const u16* Kp = Kh + (size_t)bh * SEQ * HD;
  const u16* Vp = VT + (size_t)bh * HD * SEQ;
  const int tid = threadIdx.x, w = tid >> 6, l = tid & 63;
  const int q = l & 31, hi = l >> 5;
  // Q B-frags: B[t=hi*8+j][col=q] = Q[qt*32+q][dt*16 + hi*8 + j]
  bf16x8 qf[4];
#pragma unroll
  for (int dt = 0; dt < 4; ++dt) {
    union { u16x8 u; bf16x8 v; } cv;
    cv.u = *(const u16x8*)(Qp + (size_t)(qt * 32 + q) * HD + dt * 16 + hi * 8);
    qf[dt] = cv.v;
  }
  f32x16 o0 = {}, o1 = {};
  float rs = 0.f;
  const int kbase = w * (SEQ / 2);
  for (int t = 0; t < 8; ++t) {
    const int k0 = kbase + t * 64;
    unsigned W[2][8];
#pragma unroll
    for (int kc = 0; kc < 2; ++kc) {
      // K A-frags: A[row=k=q-lane][t=hi*8+j] = K[k0+kc*32+ (l&31)][dt*16+hi*8+j]
      f32x16 sc = {};
#pragma unroll
      for (int dt = 0; dt < 4; ++dt) {
        union { u16x8 u; bf16x8 v; } cv;
        cv.u = *(const u16x8*)(Kp + (size_t)(k0 + kc * 32 + q) * HD + dt * 16 + hi * 8);
        sc = __builtin_amdgcn_mfma_f32_32x32x16_bf16(cv.v, qf[dt], sc, 0, 0, 0);
      }
      float pv[16];
#pragma unroll
      for (int r = 0; r < 16; ++r) {
        float xx = fminf(10.f, fmaxf(-10.f, sc[r]));
        float p = exp2f(xx * 1.4426950408889634f);
        rs += p;
        pv[r] = p;
      }
#pragma unroll
      for (int i = 0; i < 8; ++i)
        W[kc][i] = pack2bf(pv[2 * i], pv[2 * i + 1]);
    }
    // PV: 4 kt-chunks of 16 k; A-frag via 2 permlane32_swap each
#pragma unroll
    for (int kt = 0; kt < 4; ++kt) {
      const int kcx = kt >> 1, ktl = kt & 1;
      uint32x2 s0 = __builtin_amdgcn_permlane32_swap(W[kcx][4 * ktl + 0], W[kcx][4 * ktl + 2], false, false);
      uint32x2 s1 = __builtin_amdgcn_permlane32_swap(W[kcx][4 * ktl + 1], W[kcx][4 * ktl + 3], false, false);
      union { unsigned u[4]; bf16x8 v; } pa;
      pa.u[0] = s0[0]; pa.u[1] = s1[0]; pa.u[2] = s0[1]; pa.u[3] = s1[1];
      // V B-frags from VT: B[t=hi*8+j][col=d] = VT[dc*32+(l&31)][k0+kt*16+hi*8+j]
      {
        union { u16x8 u; bf16x8 v; } v0, v1;
        v0.u = *(const u16x8*)(Vp + (size_t)(0 * 32 + q) * SEQ + k0 + kt * 16 + hi * 8);
        v1.u = *(const u16x8*)(Vp + (size_t)(1 * 32 + q) * SEQ + k0 + kt * 16 + hi * 8);
        o0 = __builtin_amdgcn_mfma_f32_32x32x16_bf16(pa.v, v0.v, o0, 0, 0, 0);
        o1 = __builtin_amdgcn_mfma_f32_32x32x16_bf16(pa.v, v1.v, o1, 0, 0, 0);
      }
    }
  }
  // complete this wave's row sum (both hi halves hold same q set)
  rs += __shfl_xor(rs, 32);
  // combine the two k-half partials
  if (w == 1) {
#pragma unroll
    for (int r = 0; r < 16; ++r) {
      const int row = (r & 3) + 8 * (r >> 2) + 4 * hi;
      oL[row][q]      = o0[r];
      oL[row][32 + q] = o1[r];
    }
    if (hi == 0) rsL[q] = rs;
  }
  __syncthreads();
  if (w == 0) {
    const float inv_q = 1.f / (rs + rsL[q]);
#pragma unroll
    for (int r = 0; r < 16; ++r) {
      const int row = (r & 3) + 8 * (r >> 2) + 4 * hi;
      const float invr = __shfl(inv_q, row);
      const int srow = qt * 32 + row;
      const size_t base = ((size_t)b * SEQ + srow) * DEMB + h * HD;
      AO[base + q]      = f2bf((o0[r] + oL[row][q]) * invr);
      AO[base + 32 + q] = f2bf((o1[r] + oL[row][32 + q]) * invr);
    }
  }
}

// ---------------- final LN -> fp32 output -----------------------------------
__global__ void ln_out_kernel(const u16* __restrict__ src0, const float* __restrict__ bo,
                              const float* __restrict__ og, const float* __restrict__ ob,
                              float* __restrict__ out) {
  __shared__ float red[8];
  const int row = blockIdx.x;
  const u16* src = src0 + (size_t)row * DEMB;
  const int t = threadIdx.x;
  uint2 pv = *(const uint2*)(src + t * 4);
  float4 v;
  v.x = bf2f(pv.x & 0xffffu); v.y = bf2f(pv.x >> 16);
  v.z = bf2f(pv.y & 0xffffu); v.w = bf2f(pv.y >> 16);
  float4 bz = *(const float4*)(bo + t * 4);
  v.x += bz.x; v.y += bz.y; v.z += bz.z; v.w += bz.w;
  float s1 = v.x + v.y + v.z + v.w;
  float s2 = v.x * v.x + v.y * v.y + v.z * v.z + v.w * v.w;
  block_reduce2(s1, s2, red);
  const float mean = s1 * (1.f / DEMB);
  const float var = s2 * (1.f / DEMB) - mean * mean;
  const float rstd = rsqrtf(var + LN_EPS);
  float4 gg = *(const float4*)(og + t * 4);
  float4 bb = *(const float4*)(ob + t * 4);
  float4 r;
  r.x = (v.x - mean) * rstd * gg.x + bb.x;
  r.y = (v.y - mean) * rstd * gg.y + bb.y;
  r.z = (v.z - mean) * rstd * gg.z + bb.z;
  r.w = (v.w - mean) * rstd * gg.w + bb.w;
  *(float4*)(out + (size_t)row * DEMB + t * 4) = r;
}

extern "C" void kernel_launch(void* const* d_in, const int* in_sizes, int n_in,
                              void* d_out, int out_size, void* d_ws, size_t ws_size,
                              hipStream_t stream) {
  (void)in_sizes; (void)n_in; (void)out_size; (void)ws_size;
  const float* x  = (const float*)d_in[0];
  const float* Wq = (const float*)d_in[1];
  const float* bq = (const float*)d_in[2];
  const float* Wk = (const float*)d_in[3];
  const float* bk = (const float*)d_in[4];
  const float* Wv = (const float*)d_in[5];
  const float* bv = (const float*)d_in[6];
  const float* Wo = (const float*)d_in[7];
  const float* bo = (const float*)d_in[8];
  const float* qg = (const float*)d_in[9];
  const float* qb = (const float*)d_in[10];
  const float* kg = (const float*)d_in[11];
  const float* kb = (const float*)d_in[12];
  const float* vg = (const float*)d_in[13];
  const float* vb = (const float*)d_in[14];
  const float* og = (const float*)d_in[15];
  const float* ob = (const float*)d_in[16];

  // Workspace map (64 MB):
  //  [0,8)   xb (x bf16) -> Vtmp (ln_qkv V-plane) -> AO (attn out)
  //  [8,16)  wb  = Wq|Wk|Wv|Wo bf16
  //  [16,40) projb (QKV proj bf16) -> oprojb (out-proj bf16)
  //  [40,48) Qh   [48,56) Kh   [56,64) VT (V transposed [bh][d][s])
  char* ws = (char*)d_ws;
  u16* xb    = (u16*)(ws);
  u16* wb    = (u16*)(ws + ((size_t)8  << 20));
  u16* projb = (u16*)(ws + ((size_t)16 << 20));
  u16* Qh    = (u16*)(ws + ((size_t)40 << 20));
  u16* Kh    = (u16*)(ws + ((size_t)48 << 20));
  u16* VT    = (u16*)(ws + ((size_t)56 << 20));
  u16* Vtmp  = xb;
  u16* AOp   = xb;
  u16* oprojb = projb;

  cvt_kernel<<<4096, 256, 0, stream>>>(x, Wq, Wk, Wv, Wo, xb, wb);

  dim3 gqkv(32, 8, 3);
  gemm_bt<<<gqkv, 256, 0, stream>>>(xb, wb, wb + (1u << 20), wb + (2u << 20),
                                    projb, MROWS, DEMB, DEMB);

  ln_qkv_kernel<<<3 * MROWS, 256, 0, stream>>>(projb, bq, bk, bv,
                                               qg, qb, kg, kb, vg, vb,
                                               Qh, Kh, Vtmp);

  vtr_kernel<<<1024, 256, 0, stream>>>(Vtmp, VT);

  attn_kernel<<<2048, 128, 0, stream>>>(Qh, Kh, VT, AOp);

  dim3 go(32, 8, 1);
  gemm_bt<<<go, 256, 0, stream>>>(AOp, wb + (3u << 20), wb + (3u << 20), wb + (3u << 20),
                                  oprojb, MROWS, DEMB, DEMB);

  ln_out_kernel<<<MROWS, 256, 0, stream>>>(oprojb, bo, og, ob, (float*)d_out);
}

// Round 10
// 231.979 us; speedup vs baseline: 1.1072x; 1.1072x over previous
//
#include <hip/hip_runtime.h>
#include <stdint.h>
#include <stddef.h>

typedef unsigned short u16;
typedef __bf16 bf16x8 __attribute__((ext_vector_type(8)));
typedef float f32x4 __attribute__((ext_vector_type(4)));
typedef float f32x16 __attribute__((ext_vector_type(16)));
typedef u16 u16x8 __attribute__((ext_vector_type(8)));
typedef unsigned uint32x2 __attribute__((ext_vector_type(2)));

#define SEQ    1024
#define DEMB   1024
#define MROWS  4096
#define NHEAD  16
#define HD     64
#define QSCALE 0.125f
#define LN_EPS 1e-5f

// round-to-nearest-even fp32 -> bf16 (raw bits)
static __device__ __forceinline__ u16 f2bf(float f) {
  union { float f; unsigned u; } c; c.f = f;
  unsigned r = c.u + 0x7FFFu + ((c.u >> 16) & 1u);
  return (u16)(r >> 16);
}
static __device__ __forceinline__ float bf2f(unsigned h) {
  union { unsigned u; float f; } c; c.u = h << 16; return c.f;
}
// pack two fp32 -> one u32 of 2 bf16 (compiler fuses to v_cvt_pk_bf16_f32)
static __device__ __forceinline__ unsigned pack2bf(float a, float b) {
  union { __bf16 h; u16 u; } x, y; x.h = (__bf16)a; y.h = (__bf16)b;
  return (unsigned)x.u | ((unsigned)y.u << 16);
}

// async global->LDS, 16B per lane; LDS dest = wave-uniform base + lane*16
static __device__ __forceinline__ void gload16(const void* g, void* l) {
  __builtin_amdgcn_global_load_lds((const __attribute__((address_space(1))) void*)g,
                                   (__attribute__((address_space(3))) void*)l, 16, 0, 0);
}

// ---------------- fp32 -> bf16 convert: x (4M) + Wq/Wk/Wv/Wo (4M) -----------
__global__ void cvt_kernel(const float* __restrict__ x,
                           const float* __restrict__ wq, const float* __restrict__ wk,
                           const float* __restrict__ wv, const float* __restrict__ wo,
                           u16* __restrict__ xb, u16* __restrict__ wb) {
  size_t e = ((size_t)blockIdx.x * blockDim.x + threadIdx.x) * 8;
  const float* src; u16* dst; size_t off;
  if (e < (size_t)MROWS * DEMB) { src = x; dst = xb; off = e; }
  else {
    size_t we = e - (size_t)MROWS * DEMB;
    int plane = (int)(we >> 20);
    src = (plane == 0) ? wq : (plane == 1) ? wk : (plane == 2) ? wv : wo;
    dst = wb + ((size_t)plane << 20);
    off = we & ((1u << 20) - 1);
  }
  float4 a = *(const float4*)(src + off);
  float4 b = *(const float4*)(src + off + 4);
  u16 o[8] = { f2bf(a.x), f2bf(a.y), f2bf(a.z), f2bf(a.w),
               f2bf(b.x), f2bf(b.y), f2bf(b.z), f2bf(b.w) };
  uint4 pk;
  pk.x = (unsigned)o[0] | ((unsigned)o[1] << 16);
  pk.y = (unsigned)o[2] | ((unsigned)o[3] << 16);
  pk.z = (unsigned)o[4] | ((unsigned)o[5] << 16);
  pk.w = (unsigned)o[6] | ((unsigned)o[7] << 16);
  *(uint4*)(dst + off) = pk;
}

// ---------------- bf16 GEMM  C[m,n] = sum_k A[m,k] * W[n,k]  (bf16 out) -----
__global__ __launch_bounds__(256)
void gemm_bt(const u16* __restrict__ A, const u16* __restrict__ B0,
             const u16* __restrict__ B1, const u16* __restrict__ B2,
             u16* __restrict__ C, int M, int N, int K) {
  __shared__ u16 lA[128 * 32];
  __shared__ u16 lB[128 * 32];
  const u16* Bp = (blockIdx.z == 0) ? B0 : (blockIdx.z == 1) ? B1 : B2;
  u16* Cp = C + (size_t)blockIdx.z * ((size_t)M * N);
  const int tid = threadIdx.x;
  const int w = tid >> 6, l = tid & 63;
  const int lr = l & 15, lg = l >> 4;
  const int m0 = blockIdx.x * 128, n0 = blockIdx.y * 128;
  const int wm = (w & 1) * 64, wn = (w >> 1) * 64;
  f32x4 acc[4][4] = {};
  const int cid0 = w * 64 + l;
  const int cid1 = 256 + w * 64 + l;
  const int rowA0 = cid0 >> 2, kc0 = (cid0 & 3) * 8;
  const int rowA1 = cid1 >> 2, kc1 = (cid1 & 3) * 8;
  for (int kt = 0; kt < K; kt += 32) {
    __syncthreads();
    gload16(A  + (size_t)(m0 + rowA0) * K + kt + kc0, lA + (size_t)(w * 64) * 8);
    gload16(A  + (size_t)(m0 + rowA1) * K + kt + kc1, lA + (size_t)(256 + w * 64) * 8);
    gload16(Bp + (size_t)(n0 + rowA0) * K + kt + kc0, lB + (size_t)(w * 64) * 8);
    gload16(Bp + (size_t)(n0 + rowA1) * K + kt + kc1, lB + (size_t)(256 + w * 64) * 8);
    __syncthreads();
    bf16x8 af[4], bfg[4];
#pragma unroll
    for (int mb = 0; mb < 4; ++mb) {
      union { u16x8 u; bf16x8 v; } cv;
      cv.u = *(const u16x8*)(lA + (wm + mb * 16 + lr) * 32 + lg * 8);
      af[mb] = cv.v;
    }
#pragma unroll
    for (int nb = 0; nb < 4; ++nb) {
      union { u16x8 u; bf16x8 v; } cv;
      cv.u = *(const u16x8*)(lB + (wn + nb * 16 + lr) * 32 + lg * 8);
      bfg[nb] = cv.v;
    }
#pragma unroll
    for (int mb = 0; mb < 4; ++mb)
#pragma unroll
      for (int nb = 0; nb < 4; ++nb)
        acc[mb][nb] = __builtin_amdgcn_mfma_f32_16x16x32_bf16(af[mb], bfg[nb], acc[mb][nb], 0, 0, 0);
  }
#pragma unroll
  for (int mb = 0; mb < 4; ++mb)
#pragma unroll
    for (int nb = 0; nb < 4; ++nb)
#pragma unroll
      for (int r = 0; r < 4; ++r) {
        int row = m0 + wm + mb * 16 + lg * 4 + r;
        int col = n0 + wn + nb * 16 + lr;
        Cp[(size_t)row * N + col] = f2bf(acc[mb][nb][r]);
      }
}

// ---------------- block-wide (256t) sum + sumsq reduce ----------------------
static __device__ __forceinline__ void block_reduce2(float& s1, float& s2, float* red) {
#pragma unroll
  for (int o = 32; o > 0; o >>= 1) { s1 += __shfl_xor(s1, o); s2 += __shfl_xor(s2, o); }
  int w = threadIdx.x >> 6, l = threadIdx.x & 63;
  if (l == 0) { red[w * 2] = s1; red[w * 2 + 1] = s2; }
  __syncthreads();
  s1 = red[0] + red[2] + red[4] + red[6];
  s2 = red[1] + red[3] + red[5] + red[7];
}

// ---------------- LN over QKV proj rows -> bf16 head layout [B,H,S,64] ------
__global__ void ln_qkv_kernel(const u16* __restrict__ projb,
                              const float* __restrict__ bq, const float* __restrict__ bk,
                              const float* __restrict__ bv,
                              const float* __restrict__ qg, const float* __restrict__ qb,
                              const float* __restrict__ kg, const float* __restrict__ kb,
                              const float* __restrict__ vg, const float* __restrict__ vb,
                              u16* __restrict__ Qh, u16* __restrict__ Kh, u16* __restrict__ Vh) {
  __shared__ float red[8];
  const int row = blockIdx.x & (MROWS - 1);
  const int plane = blockIdx.x >> 12;
  const float* bias; const float* gam; const float* bet; u16* op; float scl;
  if (plane == 0)      { bias = bq; gam = qg; bet = qb; op = Qh; scl = QSCALE; }
  else if (plane == 1) { bias = bk; gam = kg; bet = kb; op = Kh; scl = 1.f; }
  else                 { bias = bv; gam = vg; bet = vb; op = Vh; scl = 1.f; }
  const u16* src = projb + ((size_t)plane * MROWS + row) * DEMB;
  const int t = threadIdx.x;
  uint2 pv = *(const uint2*)(src + t * 4);
  float4 v;
  v.x = bf2f(pv.x & 0xffffu); v.y = bf2f(pv.x >> 16);
  v.z = bf2f(pv.y & 0xffffu); v.w = bf2f(pv.y >> 16);
  float4 bz = *(const float4*)(bias + t * 4);
  v.x += bz.x; v.y += bz.y; v.z += bz.z; v.w += bz.w;
  float s1 = v.x + v.y + v.z + v.w;
  float s2 = v.x * v.x + v.y * v.y + v.z * v.z + v.w * v.w;
  block_reduce2(s1, s2, red);
  const float mean = s1 * (1.f / DEMB);
  const float var = s2 * (1.f / DEMB) - mean * mean;
  const float rstd = rsqrtf(var + LN_EPS);
  float4 gg = *(const float4*)(gam + t * 4);
  float4 bb = *(const float4*)(bet + t * 4);
  u16 o0 = f2bf(((v.x - mean) * rstd * gg.x + bb.x) * scl);
  u16 o1 = f2bf(((v.y - mean) * rstd * gg.y + bb.y) * scl);
  u16 o2 = f2bf(((v.z - mean) * rstd * gg.z + bb.z) * scl);
  u16 o3 = f2bf(((v.w - mean) * rstd * gg.w + bb.w) * scl);
  const int b = row >> 10, s = row & (SEQ - 1);
  const int h = t >> 4;
  u16* dst = op + ((size_t)(b * NHEAD + h) * SEQ + s) * HD + (t & 15) * 4;
  uint2 pk;
  pk.x = (unsigned)o0 | ((unsigned)o1 << 16);
  pk.y = (unsigned)o2 | ((unsigned)o3 << 16);
  *(uint2*)dst = pk;
}

// ---------------- V transpose: Vtmp[bh][s][d] -> VT[bh][d][s] ---------------
__global__ __launch_bounds__(256)
void vtr_kernel(const u16* __restrict__ Vtmp, u16* __restrict__ VT) {
  __shared__ u16 t[64][72];
  const int stile = blockIdx.x & 15, bh = blockIdx.x >> 4;
  const u16* src = Vtmp + ((size_t)bh * SEQ + stile * 64) * HD;
  const int tid = threadIdx.x;
  {
    const int c0 = tid * 2;
    const int r = c0 >> 3, c = c0 & 7;
    uint4 v0 = *(const uint4*)(src + (size_t)r * HD + c * 8);
    uint4 v1 = *(const uint4*)(src + (size_t)r * HD + (c + 1) * 8);
    *(uint4*)&t[r][c * 8] = v0;
    *(uint4*)&t[r][(c + 1) * 8] = v1;
  }
  __syncthreads();
  const int d = tid >> 2, sc = tid & 3;
  u16 buf[16];
#pragma unroll
  for (int j = 0; j < 16; ++j) buf[j] = t[sc * 16 + j][d];
  u16* dst = VT + ((size_t)bh * HD + d) * SEQ + stile * 64 + sc * 16;
  *(uint4*)(dst)     = *(uint4*)&buf[0];
  *(uint4*)(dst + 8) = *(uint4*)&buf[8];
}

// ---------------- attention v4: LDS-staged K/V (coalesced), in-reg softmax --
// 512 blocks x 4 waves; block = (bh, 128 q-rows); wave = 32 q-rows; loop over
// all 16 k-tiles (KVBLK=64). K/V staged via global_load_lds with pre-swizzled
// SOURCE (chunk ^ = row&7) + same XOR on ds_read col -> bank-uniform reads.
// Swapped QK^T (32x32x16, S^T=mfma(K,Q)) keeps softmax lane-local; P->A-frag
// via cvt_pk + permlane32_swap (round-8-verified math, unchanged).
__global__ __launch_bounds__(256)
void attn_kernel(const u16* __restrict__ Qh, const u16* __restrict__ Kh,
                 const u16* __restrict__ VT, u16* __restrict__ AO) {
  __shared__ u16 lK[64 * 64];
  __shared__ u16 lV[64 * 64];
  const int bid = blockIdx.x;
  const int wg = (bid & 7) * 64 + (bid >> 3);   // bijective: 512 = 8*64
  const int qt = wg & 7, bh = wg >> 3;          // 8 heads per XCD chunk
  const int b = bh >> 4, h = bh & 15;
  const u16* Qp = Qh + (size_t)bh * SEQ * HD;
  const u16* Kp = Kh + (size_t)bh * SEQ * HD;
  const u16* Vp = VT + (size_t)bh * HD * SEQ;
  const int tid = threadIdx.x, w = tid >> 6, l = tid & 63;
  const int q = l & 31, hi = l >> 5;
  // staging: thread covers 16B chunks c0=tid, c1=256+tid of each 8KB tile;
  // source chunk pre-swizzled (involution lc = c ^ ((c>>3)&7)) so that
  // linear LDS + XOR-on-read yields correct data with bank-uniform access.
  const int c0 = tid, c1 = 256 + tid;
  const int lc0 = c0 ^ ((c0 >> 3) & 7), lc1 = c1 ^ ((c1 >> 3) & 7);
  const int r0 = lc0 >> 3, cc0 = (lc0 & 7) * 8;
  const int r1 = lc1 >> 3, cc1 = (lc1 & 7) * 8;
  // Q B-frags: B[t=hi*8+j][col=q] = Q[qrow][dt*16 + hi*8 + j]
  bf16x8 qf[4];
  const int qrow = qt * 128 + w * 32 + q;
#pragma unroll
  for (int dt = 0; dt < 4; ++dt) {
    union { u16x8 u; bf16x8 v; } cv;
    cv.u = *(const u16x8*)(Qp + (size_t)qrow * HD + dt * 16 + hi * 8);
    qf[dt] = cv.v;
  }
  f32x16 o0 = {}, o1 = {};
  float rs = 0.f;
  const int swz = (q & 7) * 8;   // XOR on LDS column (u16 elems)
  for (int t = 0; t < 16; ++t) {
    const int k0 = t * 64;
    __syncthreads();
    gload16(Kp + (size_t)(k0 + r0) * HD + cc0, lK + (size_t)(w * 64) * 8);
    gload16(Kp + (size_t)(k0 + r1) * HD + cc1, lK + (size_t)(256 + w * 64) * 8);
    gload16(Vp + (size_t)r0 * SEQ + k0 + cc0, lV + (size_t)(w * 64) * 8);
    gload16(Vp + (size_t)r1 * SEQ + k0 + cc1, lV + (size_t)(256 + w * 64) * 8);
    __syncthreads();
    unsigned W[2][8];
#pragma unroll
    for (int kc = 0; kc < 2; ++kc) {
      // K A-frags: A[row=k][t=hi*8+j] = K[k0+kc*32+q][dt*16+hi*8+j]
      f32x16 sc = {};
#pragma unroll
      for (int dt = 0; dt < 4; ++dt) {
        union { u16x8 u; bf16x8 v; } cv;
        cv.u = *(const u16x8*)(lK + (kc * 32 + q) * 64 + ((dt * 16 + hi * 8) ^ swz));
        sc = __builtin_amdgcn_mfma_f32_32x32x16_bf16(cv.v, qf[dt], sc, 0, 0, 0);
      }
      float pv[16];
#pragma unroll
      for (int r = 0; r < 16; ++r) {
        float xx = fminf(10.f, fmaxf(-10.f, sc[r]));
        float p = exp2f(xx * 1.4426950408889634f);
        rs += p;
        pv[r] = p;
      }
#pragma unroll
      for (int i = 0; i < 8; ++i)
        W[kc][i] = pack2bf(pv[2 * i], pv[2 * i + 1]);
    }
    // PV: 4 kt-chunks of 16 k; A-frag via 2 permlane32_swap each
#pragma unroll
    for (int kt = 0; kt < 4; ++kt) {
      const int kcx = kt >> 1, ktl = kt & 1;
      uint32x2 s0 = __builtin_amdgcn_permlane32_swap(W[kcx][4 * ktl + 0], W[kcx][4 * ktl + 2], false, false);
      uint32x2 s1 = __builtin_amdgcn_permlane32_swap(W[kcx][4 * ktl + 1], W[kcx][4 * ktl + 3], false, false);
      union { unsigned u[4]; bf16x8 v; } pa;
      pa.u[0] = s0[0]; pa.u[1] = s1[0]; pa.u[2] = s0[1]; pa.u[3] = s1[1];
      // V B-frags: B[t=hi*8+j][col=d] = Vtile[d=dc*32+q][kt*16+hi*8+j]
      union { u16x8 u; bf16x8 v; } v0, v1;
      v0.u = *(const u16x8*)(lV + (q) * 64 + ((kt * 16 + hi * 8) ^ swz));
      v1.u = *(const u16x8*)(lV + (32 + q) * 64 + ((kt * 16 + hi * 8) ^ swz));
      o0 = __builtin_amdgcn_mfma_f32_32x32x16_bf16(pa.v, v0.v, o0, 0, 0, 0);
      o1 = __builtin_amdgcn_mfma_f32_32x32x16_bf16(pa.v, v1.v, o1, 0, 0, 0);
    }
  }
  // complete row sum (hi halves hold complementary k-rows of same q)
  rs += __shfl_xor(rs, 32);
  const float inv_q = 1.f / rs;
#pragma unroll
  for (int r = 0; r < 16; ++r) {
    const int row = (r & 3) + 8 * (r >> 2) + 4 * hi;
    const float invr = __shfl(inv_q, row);
    const int srow = qt * 128 + w * 32 + row;
    const size_t base = ((size_t)b * SEQ + srow) * DEMB + h * HD;
    AO[base + q]      = f2bf(o0[r] * invr);
    AO[base + 32 + q] = f2bf(o1[r] * invr);
  }
}

// ---------------- final LN -> fp32 output -----------------------------------
__global__ void ln_out_kernel(const u16* __restrict__ src0, const float* __restrict__ bo,
                              const float* __restrict__ og, const float* __restrict__ ob,
                              float* __restrict__ out) {
  __shared__ float red[8];
  const int row = blockIdx.x;
  const u16* src = src0 + (size_t)row * DEMB;
  const int t = threadIdx.x;
  uint2 pv = *(const uint2*)(src + t * 4);
  float4 v;
  v.x = bf2f(pv.x & 0xffffu); v.y = bf2f(pv.x >> 16);
  v.z = bf2f(pv.y & 0xffffu); v.w = bf2f(pv.y >> 16);
  float4 bz = *(const float4*)(bo + t * 4);
  v.x += bz.x; v.y += bz.y; v.z += bz.z; v.w += bz.w;
  float s1 = v.x + v.y + v.z + v.w;
  float s2 = v.x * v.x + v.y * v.y + v.z * v.z + v.w * v.w;
  block_reduce2(s1, s2, red);
  const float mean = s1 * (1.f / DEMB);
  const float var = s2 * (1.f / DEMB) - mean * mean;
  const float rstd = rsqrtf(var + LN_EPS);
  float4 gg = *(const float4*)(og + t * 4);
  float4 bb = *(const float4*)(ob + t * 4);
  float4 r;
  r.x = (v.x - mean) * rstd * gg.x + bb.x;
  r.y = (v.y - mean) * rstd * gg.y + bb.y;
  r.z = (v.z - mean) * rstd * gg.z + bb.z;
  r.w = (v.w - mean) * rstd * gg.w + bb.w;
  *(float4*)(out + (size_t)row * DEMB + t * 4) = r;
}

extern "C" void kernel_launch(void* const* d_in, const int* in_sizes, int n_in,
                              void* d_out, int out_size, void* d_ws, size_t ws_size,
                              hipStream_t stream) {
  (void)in_sizes; (void)n_in; (void)out_size; (void)ws_size;
  const float* x  = (const float*)d_in[0];
  const float* Wq = (const float*)d_in[1];
  const float* bq = (const float*)d_in[2];
  const float* Wk = (const float*)d_in[3];
  const float* bk = (const float*)d_in[4];
  const float* Wv = (const float*)d_in[5];
  const float* bv = (const float*)d_in[6];
  const float* Wo = (const float*)d_in[7];
  const float* bo = (const float*)d_in[8];
  const float* qg = (const float*)d_in[9];
  const float* qb = (const float*)d_in[10];
  const float* kg = (const float*)d_in[11];
  const float* kb = (const float*)d_in[12];
  const float* vg = (const float*)d_in[13];
  const float* vb = (const float*)d_in[14];
  const float* og = (const float*)d_in[15];
  const float* ob = (const float*)d_in[16];

  // Workspace map (64 MB):
  //  [0,8)   xb (x bf16) -> Vtmp (ln_qkv V-plane) -> AO (attn out)
  //  [8,16)  wb  = Wq|Wk|Wv|Wo bf16
  //  [16,40) projb (QKV proj bf16) -> oprojb (out-proj bf16)
  //  [40,48) Qh   [48,56) Kh   [56,64) VT (V transposed [bh][d][s])
  char* ws = (char*)d_ws;
  u16* xb    = (u16*)(ws);
  u16* wb    = (u16*)(ws + ((size_t)8  << 20));
  u16* projb = (u16*)(ws + ((size_t)16 << 20));
  u16* Qh    = (u16*)(ws + ((size_t)40 << 20));
  u16* Kh    = (u16*)(ws + ((size_t)48 << 20));
  u16* VT    = (u16*)(ws + ((size_t)56 << 20));
  u16* Vtmp  = xb;
  u16* AOp   = xb;
  u16* oprojb = projb;

  cvt_kernel<<<4096, 256, 0, stream>>>(x, Wq, Wk, Wv, Wo, xb, wb);

  dim3 gqkv(32, 8, 3);
  gemm_bt<<<gqkv, 256, 0, stream>>>(xb, wb, wb + (1u << 20), wb + (2u << 20),
                                    projb, MROWS, DEMB, DEMB);

  ln_qkv_kernel<<<3 * MROWS, 256, 0, stream>>>(projb, bq, bk, bv,
                                               qg, qb, kg, kb, vg, vb,
                                               Qh, Kh, Vtmp);

  vtr_kernel<<<1024, 256, 0, stream>>>(Vtmp, VT);

  attn_kernel<<<512, 256, 0, stream>>>(Qh, Kh, VT, AOp);

  dim3 go(32, 8, 1);
  gemm_bt<<<go, 256, 0, stream>>>(AOp, wb + (3u << 20), wb + (3u << 20), wb + (3u << 20),
                                  oprojb, MROWS, DEMB, DEMB);

  ln_out_kernel<<<MROWS, 256, 0, stream>>>(oprojb, bo, og, ob, (float*)d_out);
}